// Round 12
// baseline (244.293 us; speedup 1.0000x reference)
//
#include <hip/hip_runtime.h>
#include <hip/hip_bf16.h>

#define NB 5
#define NS 1024
#define NC 320
#define NH 8
#define ND 40
#define NKF 3
#define NBS (NB*NS)     // 5120
#define NL (NKF*NS)     // 3072
#define HP 48           // per-head padded d (40 -> 48) for Q
#define QSTR 384        // q row stride = 8 heads * 48
#define KTILE (32*48)   // K tile: [tok32][d48]
#define VTILE (64*32)   // V tile: [d64][tok32]

typedef __attribute__((ext_vector_type(4))) float f32x4;
typedef __attribute__((ext_vector_type(16))) float f32x16;
typedef __attribute__((ext_vector_type(8))) short bf16x8;
typedef __attribute__((ext_vector_type(4))) unsigned u32x4;

#define MFMA16(a,b,c) __builtin_amdgcn_mfma_f32_16x16x32_bf16((a),(b),(c),0,0,0)
#define MFMA32(a,b,c) __builtin_amdgcn_mfma_f32_32x32x16_bf16((a),(b),(c),0,0,0)

// 1/sqrt(40) * log2(e): scores produced directly in log2 domain
#define QSCALE2 0.22811012f

// un-sinkable 16B global load (keeps tile loads batched & in flight)
#define GLOAD(dst, ptr) asm volatile("global_load_dwordx4 %0, %1, off" : "=v"(dst) : "v"(ptr))
// wait until <=7 vmem ops outstanding (the other tile's 7 stay in flight);
// sched_barrier(0) per rule #18 so consumers can't hoist above the wait
#define WAIT7() do{ asm volatile("s_waitcnt vmcnt(7)" ::: "memory"); __builtin_amdgcn_sched_barrier(0); }while(0)

__device__ inline float ex2(float x){
  float r;
  asm("v_exp_f32 %0, %1" : "=v"(r) : "v"(x));
  return r;
}

__device__ inline unsigned short f2bf(float f){
  unsigned int u = __builtin_bit_cast(unsigned int, f);
  u += 0x7fffu + ((u >> 16) & 1u);
  return (unsigned short)(u >> 16);
}

__device__ inline unsigned pkbf(float lo, float hi){
  unsigned r;
  asm("v_cvt_pk_bf16_f32 %0, %1, %2" : "=v"(r) : "v"(lo), "v"(hi));
  return r;
}

// ---- prep: hs fp32 -> bf16 ----
__global__ __launch_bounds__(256) void k_conv_hs(const float* __restrict__ hs,
                                                 unsigned short* __restrict__ hsb){
  int i = (blockIdx.x * 256 + threadIdx.x) * 4;
  float4 v = *(const float4*)&hs[i];
  ushort4 o;
  o.x = f2bf(v.x); o.y = f2bf(v.y); o.z = f2bf(v.z); o.w = f2bf(v.w);
  *(ushort4*)&hsb[i] = o;
}

// ---- prep: W (k,n) fp32 -> W^T (n,k) bf16; Wq folds scale*log2e ----
__global__ void k_conv_w(const float* __restrict__ wq, const float* __restrict__ wk,
                         const float* __restrict__ wv, const float* __restrict__ wo,
                         unsigned short* __restrict__ wqT, unsigned short* __restrict__ wkT,
                         unsigned short* __restrict__ wvT, unsigned short* __restrict__ woT){
  int k = blockIdx.x * 16 + threadIdx.x;
  int n = blockIdx.y * 16 + threadIdx.y;
  const float* src; unsigned short* dst; float scl = 1.0f;
  switch (blockIdx.z){
    case 0: src = wq; dst = wqT; scl = QSCALE2; break;
    case 1: src = wk; dst = wkT; break;
    case 2: src = wv; dst = wvT; break;
    default: src = wo; dst = woT; break;
  }
  dst[n*NC + k] = f2bf(src[k*NC + n] * scl);
}

// ---- prep: zero Q pad slots (d 40..47 of each head) ----
__global__ __launch_bounds__(256) void k_zero_qbpad(unsigned short* __restrict__ qbp){
  int t = blockIdx.x * 256 + threadIdx.x;   // token*8 + h
  int token = t >> 3, hh = t & 7;
  bf16x8 z = {0,0,0,0,0,0,0,0};
  *(bf16x8*)&qbp[token*QSTR + hh*HP + ND] = z;
}

// ---- QKV projection GEMM ----
// Q: padded [token][h*48+d], scale folded. K: tiled [tokblk][h][tok32][d48].
// V: tiled [tokblk][h][d64][tok32].
__global__ __launch_bounds__(256) void k_qkv(const unsigned short* __restrict__ hsb,
    const unsigned short* __restrict__ wqT, const unsigned short* __restrict__ wkT,
    const unsigned short* __restrict__ wvT,
    unsigned short* __restrict__ qb, unsigned short* __restrict__ kb,
    unsigned short* __restrict__ vT){
  int wave = threadIdx.x >> 6, lane = threadIdx.x & 63;
  int lane16 = lane & 15, grp = lane >> 4;
  int m0 = blockIdx.x * 64, n0 = blockIdx.y * 64;
  int mat = blockIdx.z;
  const unsigned short* wT = (mat == 0) ? wqT : ((mat == 1) ? wkT : wvT);
  int arow = m0 + wave * 16 + lane16;
  f32x4 acc[4];
  #pragma unroll
  for (int t = 0; t < 4; t++) acc[t] = (f32x4){0.f,0.f,0.f,0.f};
  #pragma unroll
  for (int k0 = 0; k0 < NC; k0 += 32){
    bf16x8 a = *(const bf16x8*)&hsb[arow*NC + k0 + grp*8];
    #pragma unroll
    for (int t = 0; t < 4; t++){
      bf16x8 b = *(const bf16x8*)&wT[(n0 + t*16 + lane16)*NC + k0 + grp*8];
      acc[t] = MFMA16(a, b, acc[t]);
    }
  }
  int crow = m0 + wave * 16 + grp * 4;
  #pragma unroll
  for (int t = 0; t < 4; t++){
    int cc = n0 + t*16 + lane16;
    int hh = cc / ND, dd = cc - hh*ND;
    #pragma unroll
    for (int r = 0; r < 4; r++){
      unsigned short val = f2bf(acc[t][r]);
      int rr = crow + r;
      int tokblk = rr >> 5, tl = rr & 31;
      if (mat == 0)      qb[rr*QSTR + hh*HP + dd] = val;
      else if (mat == 1) kb[(((size_t)tokblk*NH + hh)*32 + tl)*HP + dd] = val;
      else               vT[(((size_t)tokblk*NH + hh)*64 + dd)*32 + tl] = val;
    }
  }
}

// ---- attention: swapped-operand 32x32 MFMA, tiled K/V, kv-split x3,
//      XCD-pinned heads (h = blockIdx.x & 7), asm-batched double-buffered
//      tile loads with counted vmcnt(7).
//      amdgpu_waves_per_eu(2,3): cap allocator's occupancy target at 3
//      waves/EU (budget ~170 VGPR) so the ~150-reg live set stays in
//      registers instead of being spilled for occupancy it can't use ----
__global__ __launch_bounds__(192)
__attribute__((amdgpu_waves_per_eu(2, 3)))
void k_attn(const unsigned short* __restrict__ qb,
    const unsigned short* __restrict__ kb, const unsigned short* __restrict__ vT,
    const int* __restrict__ ids, unsigned short* __restrict__ ao){
  __shared__ float ldsO[NKF][32][64];
  __shared__ float ldsM[NKF][32];
  __shared__ float ldsL[NKF][32];
  __shared__ float ldsCF[NKF][32];
  int w = threadIdx.x >> 6, lane = threadIdx.x & 63;
  int l31 = lane & 31, hi = lane >> 5;
  int b = blockIdx.z;
  int h = blockIdx.x & 7;           // XCD-pinned head
  int q0 = (blockIdx.x >> 3) * 32;
  int frame = ids[b*NKF + w];

  // Q B-fragments, 3 k-steps of 16 covering d 0..47 (40..47 zero-padded)
  bf16x8 qf0, qf1, qf2;
  {
    int qoff = (b*NS + q0 + l31) * QSTR + h*HP + hi*8;
    qf0 = *(const bf16x8*)&qb[qoff];
    qf1 = *(const bf16x8*)&qb[qoff + 16];
    qf2 = *(const bf16x8*)&qb[qoff + 32];
  }

  // loop-invariant per-lane bases into the tiled K/V
  const unsigned short* kbase = kb + ((size_t)(frame*32)*NH + h)*KTILE + l31*HP + hi*8;
  const unsigned short* vbase = vT + ((size_t)(frame*32)*NH + h)*VTILE + l31*32 + hi*8;
  const size_t KSTEP = (size_t)NH*KTILE, VSTEP = (size_t)NH*VTILE;

  f32x16 o0, o1;
  #pragma unroll
  for (int r = 0; r < 16; r++){ o0[r] = 0.f; o1[r] = 0.f; }
  const f32x16 z16 = o0;
  float m2 = -1e30f, lsum = 0.f;

  auto body = [&](bf16x8 k0, bf16x8 k1, bf16x8 k2,
                  bf16x8 v00, bf16x8 v01, bf16x8 v10, bf16x8 v11){
    f32x16 s = MFMA32(k0, qf0, z16);
    s = MFMA32(k1, qf1, s);
    s = MFMA32(k2, qf2, s);
    // lane holds S^T (log2 domain): col q = l31, rows kv = (r&3)+8*(r>>2)+4*hi

    float t0 = fmaxf(fmaxf(s[0], s[1]), s[2]);
    float t1 = fmaxf(fmaxf(s[3], s[4]), s[5]);
    float t2 = fmaxf(fmaxf(s[6], s[7]), s[8]);
    float t3 = fmaxf(fmaxf(s[9], s[10]), s[11]);
    float t4 = fmaxf(fmaxf(s[12], s[13]), s[14]);
    float pmax = fmaxf(fmaxf(fmaxf(t0, t1), fmaxf(t2, t3)), fmaxf(t4, s[15]));
    pmax = fmaxf(pmax, __shfl_xor(pmax, 32));

    if (!__all(pmax - m2 <= 8.0f)){       // defer-max: rescale only on real growth
      float mnew = fmaxf(m2, pmax);
      float cf = ex2(m2 - mnew);
      lsum *= cf;
      if (lane < 32) ldsCF[w][l31] = cf;
      #pragma unroll
      for (int r = 0; r < 16; r++){
        float c = ldsCF[w][(r&3) + 8*(r>>2) + 4*hi];
        o0[r] *= c; o1[r] *= c;
      }
      m2 = mnew;
    }

    float p[16];
    #pragma unroll
    for (int r = 0; r < 16; r++) p[r] = ex2(s[r] - m2);
    float a0 = (p[0]+p[1]) + (p[2]+p[3]);
    float a1 = (p[4]+p[5]) + (p[6]+p[7]);
    float a2 = (p[8]+p[9]) + (p[10]+p[11]);
    float a3 = (p[12]+p[13]) + (p[14]+p[15]);
    float ts = (a0+a1) + (a2+a3);
    ts += __shfl_xor(ts, 32);
    lsum += ts;

    // P -> A-fragments for PV (2 k-steps of 16): cvt_pk pairs + one xor-32 exchange
    u32x4 pw0, pw1;
    #pragma unroll
    for (int ks = 0; ks < 2; ks++){
      int qa = 2*ks + hi;         // local quad
      int qp = 2*ks + 1 - hi;     // quad built for partner
      unsigned A0 = pkbf(p[4*qa+0], p[4*qa+1]);
      unsigned A1 = pkbf(p[4*qa+2], p[4*qa+3]);
      unsigned B0 = pkbf(p[4*qp+0], p[4*qp+1]);
      unsigned B1 = pkbf(p[4*qp+2], p[4*qp+3]);
      unsigned R0 = (unsigned)__shfl_xor((int)B0, 32);
      unsigned R1 = (unsigned)__shfl_xor((int)B1, 32);
      u32x4 wd;
      if (hi == 0){ wd[0]=A0; wd[1]=A1; wd[2]=R0; wd[3]=R1; }
      else        { wd[0]=R0; wd[1]=R1; wd[2]=A0; wd[3]=A1; }
      if (ks == 0) pw0 = wd; else pw1 = wd;
    }
    bf16x8 pa0 = __builtin_bit_cast(bf16x8, pw0);
    bf16x8 pa1 = __builtin_bit_cast(bf16x8, pw1);

    o0 = MFMA32(pa0, v00, o0);
    o0 = MFMA32(pa1, v01, o0);
    o1 = MFMA32(pa0, v10, o1);
    o1 = MFMA32(pa1, v11, o1);
  };

  // double-buffered asm-batched tile loads
  bf16x8 Ak0,Ak1,Ak2,Av0,Av1,Av2,Av3, Bk0,Bk1,Bk2,Bv0,Bv1,Bv2,Bv3;
  GLOAD(Ak0, kbase); GLOAD(Ak1, kbase+16); GLOAD(Ak2, kbase+32);
  GLOAD(Av0, vbase); GLOAD(Av1, vbase+16); GLOAD(Av2, vbase+1024); GLOAD(Av3, vbase+1024+16);

  for (int kvb = 0; kvb < NS/32; kvb += 2){
    {
      const unsigned short* kp = kbase + (size_t)(kvb+1)*KSTEP;
      const unsigned short* vp = vbase + (size_t)(kvb+1)*VSTEP;
      GLOAD(Bk0, kp); GLOAD(Bk1, kp+16); GLOAD(Bk2, kp+32);
      GLOAD(Bv0, vp); GLOAD(Bv1, vp+16); GLOAD(Bv2, vp+1024); GLOAD(Bv3, vp+1024+16);
    }
    WAIT7();                       // A complete (B's 7 still in flight)
    body(Ak0,Ak1,Ak2,Av0,Av1,Av2,Av3);
    {
      int nx = kvb + 2; if (nx > NS/32 - 1) nx = NS/32 - 1;
      const unsigned short* kp = kbase + (size_t)nx*KSTEP;
      const unsigned short* vp = vbase + (size_t)nx*VSTEP;
      GLOAD(Ak0, kp); GLOAD(Ak1, kp+16); GLOAD(Ak2, kp+32);
      GLOAD(Av0, vp); GLOAD(Av1, vp+16); GLOAD(Av2, vp+1024); GLOAD(Av3, vp+1024+16);
    }
    WAIT7();                       // B complete (A's 7 still in flight)
    body(Bk0,Bk1,Bk2,Bv0,Bv1,Bv2,Bv3);
  }

  // write partials to LDS
  #pragma unroll
  for (int r = 0; r < 16; r++){
    int qq = (r&3) + 8*(r>>2) + 4*hi;
    ldsO[w][qq][l31]      = o0[r];
    ldsO[w][qq][32 + l31] = o1[r];
  }
  if (lane < 32){ ldsM[w][l31] = m2; ldsL[w][l31] = lsum; }
  __syncthreads();

  // merge 3 kv-split partials and store
  for (int t = threadIdx.x; t < 32*ND; t += 192){
    int qq = t / ND, d = t - (t / ND) * ND;
    float mA = ldsM[0][qq], mB = ldsM[1][qq], mC = ldsM[2][qq];
    float M = fmaxf(fmaxf(mA, mB), mC);
    float eA = ex2(mA - M), eB = ex2(mB - M), eC = ex2(mC - M);
    float L = ldsL[0][qq]*eA + ldsL[1][qq]*eB + ldsL[2][qq]*eC;
    float O = ldsO[0][qq][d]*eA + ldsO[1][qq][d]*eB + ldsO[2][qq][d]*eC;
    ao[(size_t)(b*NS + q0 + qq)*NC + h*ND + d] = f2bf(O / L);
  }
}

// ---- output projection + bias + residual (fp32 out) ----
__global__ __launch_bounds__(256) void k_out(const unsigned short* __restrict__ ao,
    const unsigned short* __restrict__ woT, const float* __restrict__ bo,
    const float* __restrict__ hs, float* __restrict__ out){
  int wave = threadIdx.x >> 6, lane = threadIdx.x & 63;
  int lane16 = lane & 15, grp = lane >> 4;
  int m0 = blockIdx.x * 64, n0 = blockIdx.y * 64;
  int arow = m0 + wave*16 + lane16;
  f32x4 acc[4];
  #pragma unroll
  for (int t = 0; t < 4; t++) acc[t] = (f32x4){0.f,0.f,0.f,0.f};
  #pragma unroll
  for (int k0 = 0; k0 < NC; k0 += 32){
    bf16x8 a = *(const bf16x8*)&ao[arow*NC + k0 + grp*8];
    #pragma unroll
    for (int t = 0; t < 4; t++){
      bf16x8 b = *(const bf16x8*)&woT[(n0 + t*16 + lane16)*NC + k0 + grp*8];
      acc[t] = MFMA16(a, b, acc[t]);
    }
  }
  int crow = m0 + wave*16 + grp*4;
  #pragma unroll
  for (int t = 0; t < 4; t++){
    int cc = n0 + t*16 + lane16;
    #pragma unroll
    for (int r = 0; r < 4; r++){
      int rr = crow + r;
      out[rr*NC + cc] = acc[t][r] + bo[cc] + hs[rr*NC + cc];
    }
  }
}

extern "C" void kernel_launch(void* const* d_in, const int* in_sizes, int n_in,
                              void* d_out, int out_size, void* d_ws, size_t ws_size,
                              hipStream_t stream){
  const float* hs = (const float*)d_in[0];
  const float* Wq = (const float*)d_in[1];
  const float* Wk = (const float*)d_in[2];
  const float* Wv = (const float*)d_in[3];
  const float* Wo = (const float*)d_in[4];
  const float* bo = (const float*)d_in[5];
  const int*  ids = (const int*)d_in[6];
  float* out = (float*)d_out;

  unsigned short* hsb = (unsigned short*)d_ws;        // aliased: ao reuses hsb
  unsigned short* wqT = hsb + (size_t)NBS*NC;
  unsigned short* wkT = wqT + (size_t)NC*NC;
  unsigned short* wvT = wkT + (size_t)NC*NC;
  unsigned short* woT = wvT + (size_t)NC*NC;
  unsigned short* qb  = woT + (size_t)NC*NC;          // [NBS][384] padded
  unsigned short* kb  = qb  + (size_t)NBS*QSTR;       // [160][8][32][48]
  unsigned short* vT  = kb  + (size_t)(NBS/32)*NH*KTILE; // [160][8][64][32]
  unsigned short* ao  = hsb;                          // safe: hsb dead after k_qkv

  k_conv_hs<<<dim3(NBS*NC/1024), dim3(256), 0, stream>>>(hs, hsb);
  k_conv_w<<<dim3(NC/16, NC/16, 4), dim3(16,16), 0, stream>>>(Wq, Wk, Wv, Wo, wqT, wkT, wvT, woT);
  k_zero_qbpad<<<dim3(NBS*NH/256), dim3(256), 0, stream>>>(qb);
  k_qkv<<<dim3(NBS/64, NC/64, 3), dim3(256), 0, stream>>>(hsb, wqT, wkT, wvT, qb, kb, vT);
  k_attn<<<dim3((NS/32)*NH, 1, NB), dim3(192), 0, stream>>>(qb, kb, vT, ids, ao);
  k_out<<<dim3(NBS/64, NC/64, 1), dim3(256), 0, stream>>>(ao, woT, bo, hs, out);
}

// Round 13
// 241.800 us; speedup vs baseline: 1.0103x; 1.0103x over previous
//
#include <hip/hip_runtime.h>
#include <hip/hip_bf16.h>

#define NB 5
#define NS 1024
#define NC 320
#define NH 8
#define ND 40
#define NKF 3
#define NBS (NB*NS)     // 5120
#define NL (NKF*NS)     // 3072
#define HP 48           // per-head padded d (40 -> 48) for Q
#define QSTR 384        // q row stride = 8 heads * 48
#define TSH 2048        // K/V tile size in shorts (4KB): K [32][64sh], V [64][32sh]

typedef __attribute__((ext_vector_type(4))) float f32x4;
typedef __attribute__((ext_vector_type(16))) float f32x16;
typedef __attribute__((ext_vector_type(8))) short bf16x8;
typedef __attribute__((ext_vector_type(4))) unsigned u32x4;

#define MFMA16(a,b,c) __builtin_amdgcn_mfma_f32_16x16x32_bf16((a),(b),(c),0,0,0)
#define MFMA32(a,b,c) __builtin_amdgcn_mfma_f32_32x32x16_bf16((a),(b),(c),0,0,0)

// 1/sqrt(40) * log2(e): scores produced directly in log2 domain
#define QSCALE2 0.22811012f

__device__ inline float ex2(float x){
  float r;
  asm("v_exp_f32 %0, %1" : "=v"(r) : "v"(x));
  return r;
}

__device__ inline unsigned short f2bf(float f){
  unsigned int u = __builtin_bit_cast(unsigned int, f);
  u += 0x7fffu + ((u >> 16) & 1u);
  return (unsigned short)(u >> 16);
}

__device__ inline unsigned pkbf(float lo, float hi){
  unsigned r;
  asm("v_cvt_pk_bf16_f32 %0, %1, %2" : "=v"(r) : "v"(lo), "v"(hi));
  return r;
}

// async global->LDS, 16B per lane: LDS dest = uniform base + lane*16
__device__ inline void stage16(const unsigned short* g, const unsigned short* l){
  __builtin_amdgcn_global_load_lds(
    (const __attribute__((address_space(1))) unsigned int*)(g),
    (__attribute__((address_space(3))) unsigned int*)(l),
    16, 0, 0);
}

// ---- prep: hs fp32 -> bf16 ----
__global__ __launch_bounds__(256) void k_conv_hs(const float* __restrict__ hs,
                                                 unsigned short* __restrict__ hsb){
  int i = (blockIdx.x * 256 + threadIdx.x) * 4;
  float4 v = *(const float4*)&hs[i];
  ushort4 o;
  o.x = f2bf(v.x); o.y = f2bf(v.y); o.z = f2bf(v.z); o.w = f2bf(v.w);
  *(ushort4*)&hsb[i] = o;
}

// ---- prep: W (k,n) fp32 -> W^T (n,k) bf16; Wq folds scale*log2e ----
__global__ void k_conv_w(const float* __restrict__ wq, const float* __restrict__ wk,
                         const float* __restrict__ wv, const float* __restrict__ wo,
                         unsigned short* __restrict__ wqT, unsigned short* __restrict__ wkT,
                         unsigned short* __restrict__ wvT, unsigned short* __restrict__ woT){
  int k = blockIdx.x * 16 + threadIdx.x;
  int n = blockIdx.y * 16 + threadIdx.y;
  const float* src; unsigned short* dst; float scl = 1.0f;
  switch (blockIdx.z){
    case 0: src = wq; dst = wqT; scl = QSCALE2; break;
    case 1: src = wk; dst = wkT; break;
    case 2: src = wv; dst = wvT; break;
    default: src = wo; dst = woT; break;
  }
  dst[n*NC + k] = f2bf(src[k*NC + n] * scl);
}

// ---- prep: zero Q pad slots (d 40..47 of each head) ----
__global__ __launch_bounds__(256) void k_zero_qbpad(unsigned short* __restrict__ qbp){
  int t = blockIdx.x * 256 + threadIdx.x;   // token*8 + h
  int token = t >> 3, hh = t & 7;
  bf16x8 z = {0,0,0,0,0,0,0,0};
  *(bf16x8*)&qbp[token*QSTR + hh*HP + ND] = z;
}

// ---- QKV projection GEMM ----
// Q: padded [token][h*48+d], scale folded.
// K: tiled+swizzled [tokblk][h][tl][chunk^(tl&7)][8]  (rows 128B)
// V: tiled+swizzled [tokblk][h][d][chunk^(d&3)][8]    (rows 64B)
__global__ __launch_bounds__(256) void k_qkv(const unsigned short* __restrict__ hsb,
    const unsigned short* __restrict__ wqT, const unsigned short* __restrict__ wkT,
    const unsigned short* __restrict__ wvT,
    unsigned short* __restrict__ qb, unsigned short* __restrict__ kb,
    unsigned short* __restrict__ vT){
  int wave = threadIdx.x >> 6, lane = threadIdx.x & 63;
  int lane16 = lane & 15, grp = lane >> 4;
  int m0 = blockIdx.x * 64, n0 = blockIdx.y * 64;
  int mat = blockIdx.z;
  const unsigned short* wT = (mat == 0) ? wqT : ((mat == 1) ? wkT : wvT);
  int arow = m0 + wave * 16 + lane16;
  f32x4 acc[4];
  #pragma unroll
  for (int t = 0; t < 4; t++) acc[t] = (f32x4){0.f,0.f,0.f,0.f};
  #pragma unroll
  for (int k0 = 0; k0 < NC; k0 += 32){
    bf16x8 a = *(const bf16x8*)&hsb[arow*NC + k0 + grp*8];
    #pragma unroll
    for (int t = 0; t < 4; t++){
      bf16x8 b = *(const bf16x8*)&wT[(n0 + t*16 + lane16)*NC + k0 + grp*8];
      acc[t] = MFMA16(a, b, acc[t]);
    }
  }
  int crow = m0 + wave * 16 + grp * 4;
  #pragma unroll
  for (int t = 0; t < 4; t++){
    int cc = n0 + t*16 + lane16;
    int hh = cc / ND, dd = cc - hh*ND;
    #pragma unroll
    for (int r = 0; r < 4; r++){
      unsigned short val = f2bf(acc[t][r]);
      int rr = crow + r;
      int tokblk = rr >> 5, tl = rr & 31;
      size_t tb = ((size_t)tokblk*NH + hh) << 11;   // tile base (2048 shorts)
      if (mat == 0)      qb[rr*QSTR + hh*HP + dd] = val;
      else if (mat == 1) kb[tb + tl*64 + (((dd>>3) ^ (tl&7)) << 3) + (dd&7)] = val;
      else               vT[tb + dd*32 + (((tl>>3) ^ (dd&3)) << 3) + (tl&7)] = val;
    }
  }
}

// ---- attention: swapped-operand 32x32 MFMA, kv-split x3, XCD-pinned heads,
//      global_load_lds double-buffered per-wave LDS staging (no staging VGPRs),
//      counted vmcnt(7), XOR-swizzled conflict-free ds_read_b128 tiles ----
__global__ __launch_bounds__(192, 2) void k_attn(const unsigned short* __restrict__ qb,
    const unsigned short* __restrict__ kb, const unsigned short* __restrict__ vT,
    const int* __restrict__ ids, unsigned short* __restrict__ ao){
  // staging (43KB) overlaid with merge buffers (25.7KB, used only after the loop)
  __shared__ union {
    unsigned short stg[NKF][2][3584];   // [wave][buf][K 2048 | V 1536]
    struct { float O[NKF][32][64]; float M[NKF][32]; float L[NKF][32]; } m;
  } sh;
  __shared__ float ldsCF[NKF][32];

  int w = threadIdx.x >> 6, lane = threadIdx.x & 63;
  int l31 = lane & 31, hi = lane >> 5;
  int b = blockIdx.z;
  int h = blockIdx.x & 7;           // XCD-pinned head
  int q0 = (blockIdx.x >> 3) * 32;
  int frame = ids[b*NKF + w];

  // Q B-fragments, 3 k-steps of 16 covering d 0..47 (40..47 zero-padded)
  bf16x8 qf0, qf1, qf2;
  {
    int qoff = (b*NS + q0 + l31) * QSTR + h*HP + hi*8;
    qf0 = *(const bf16x8*)&qb[qoff];
    qf1 = *(const bf16x8*)&qb[qoff + 16];
    qf2 = *(const bf16x8*)&qb[qoff + 32];
  }

  f32x16 o0, o1;
  #pragma unroll
  for (int r = 0; r < 16; r++){ o0[r] = 0.f; o1[r] = 0.f; }
  const f32x16 z16 = o0;
  float m2 = -1e30f, lsum = 0.f;

  // stage tile t into buffer bufi: K 4KB (4 instr) + V rows 0..47 3KB (3 instr)
  auto stage = [&](int t, int bufi){
    size_t tb = ((size_t)(frame*32 + t)*NH + h) << 11;
    const unsigned short* gk = kb + tb;
    const unsigned short* gv = vT + tb;
    const unsigned short* sk = &sh.stg[w][bufi][0];
    const unsigned short* sv = &sh.stg[w][bufi][2048];
    #pragma unroll
    for (int i = 0; i < 4; i++) stage16(gk + i*512 + lane*8, sk + i*512);
    #pragma unroll
    for (int i = 0; i < 3; i++) stage16(gv + i*512 + lane*8, sv + i*512);
  };

  auto body = [&](int bufi){
    const unsigned short* kl = &sh.stg[w][bufi][0];
    const unsigned short* vl = &sh.stg[w][bufi][2048];
    // K fragments (swizzled read): frag j covers d 16j+8hi..+8, chunk c=2j+hi
    bf16x8 k0 = *(const bf16x8*)&kl[l31*64 + (((  hi) ^ (l31&7)) << 3)];
    bf16x8 k1 = *(const bf16x8*)&kl[l31*64 + (((2+hi) ^ (l31&7)) << 3)];
    bf16x8 k2 = *(const bf16x8*)&kl[l31*64 + (((4+hi) ^ (l31&7)) << 3)];

    f32x16 s = MFMA32(k0, qf0, z16);
    s = MFMA32(k1, qf1, s);
    s = MFMA32(k2, qf2, s);
    // lane holds S^T (log2 domain): col q = l31, rows kv = (r&3)+8*(r>>2)+4*hi

    float t0 = fmaxf(fmaxf(s[0], s[1]), s[2]);
    float t1 = fmaxf(fmaxf(s[3], s[4]), s[5]);
    float t2 = fmaxf(fmaxf(s[6], s[7]), s[8]);
    float t3 = fmaxf(fmaxf(s[9], s[10]), s[11]);
    float t4 = fmaxf(fmaxf(s[12], s[13]), s[14]);
    float pmax = fmaxf(fmaxf(fmaxf(t0, t1), fmaxf(t2, t3)), fmaxf(t4, s[15]));
    pmax = fmaxf(pmax, __shfl_xor(pmax, 32));

    if (!__all(pmax - m2 <= 8.0f)){       // defer-max: rescale only on real growth
      float mnew = fmaxf(m2, pmax);
      float cf = ex2(m2 - mnew);
      lsum *= cf;
      if (lane < 32) ldsCF[w][l31] = cf;
      #pragma unroll
      for (int r = 0; r < 16; r++){
        float c = ldsCF[w][(r&3) + 8*(r>>2) + 4*hi];
        o0[r] *= c; o1[r] *= c;
      }
      m2 = mnew;
    }

    float p[16];
    #pragma unroll
    for (int r = 0; r < 16; r++) p[r] = ex2(s[r] - m2);
    float a0 = (p[0]+p[1]) + (p[2]+p[3]);
    float a1 = (p[4]+p[5]) + (p[6]+p[7]);
    float a2 = (p[8]+p[9]) + (p[10]+p[11]);
    float a3 = (p[12]+p[13]) + (p[14]+p[15]);
    float ts = (a0+a1) + (a2+a3);
    ts += __shfl_xor(ts, 32);
    lsum += ts;

    // P -> A-fragments for PV: cvt_pk pairs + one xor-32 exchange
    u32x4 pw0, pw1;
    #pragma unroll
    for (int ks = 0; ks < 2; ks++){
      int qa = 2*ks + hi;         // local quad
      int qp = 2*ks + 1 - hi;     // quad built for partner
      unsigned A0 = pkbf(p[4*qa+0], p[4*qa+1]);
      unsigned A1 = pkbf(p[4*qa+2], p[4*qa+3]);
      unsigned B0 = pkbf(p[4*qp+0], p[4*qp+1]);
      unsigned B1 = pkbf(p[4*qp+2], p[4*qp+3]);
      unsigned R0 = (unsigned)__shfl_xor((int)B0, 32);
      unsigned R1 = (unsigned)__shfl_xor((int)B1, 32);
      u32x4 wd;
      if (hi == 0){ wd[0]=A0; wd[1]=A1; wd[2]=R0; wd[3]=R1; }
      else        { wd[0]=R0; wd[1]=R1; wd[2]=A0; wd[3]=A1; }
      if (ks == 0) pw0 = wd; else pw1 = wd;
    }
    bf16x8 pa0 = __builtin_bit_cast(bf16x8, pw0);
    bf16x8 pa1 = __builtin_bit_cast(bf16x8, pw1);

    // V fragments just-in-time (swizzled read): row dr, chunk c -> c^(dr&3)
    bf16x8 v00 = *(const bf16x8*)&vl[ l31      *32 + (((  hi) ^ (l31&3)) << 3)];
    bf16x8 v01 = *(const bf16x8*)&vl[ l31      *32 + (((2+hi) ^ (l31&3)) << 3)];
    bf16x8 v10 = *(const bf16x8*)&vl[(32+l31)*32 + (((  hi) ^ (l31&3)) << 3)];
    bf16x8 v11 = *(const bf16x8*)&vl[(32+l31)*32 + (((2+hi) ^ (l31&3)) << 3)];

    o0 = MFMA32(pa0, v00, o0);
    o0 = MFMA32(pa1, v01, o0);
    o1 = MFMA32(pa0, v10, o1);
    o1 = MFMA32(pa1, v11, o1);
  };

  // pipeline: stage(t+1) in flight while computing t; counted vmcnt keeps
  // next tile's 7 loads outstanding across the body
  stage(0, 0);
  int cur = 0;
  for (int t = 0; t < NS/32 - 1; ++t){
    stage(t + 1, cur ^ 1);
    asm volatile("s_waitcnt vmcnt(7)" ::: "memory");
    __builtin_amdgcn_sched_barrier(0);
    body(cur);
    cur ^= 1;
  }
  asm volatile("s_waitcnt vmcnt(0)" ::: "memory");
  __builtin_amdgcn_sched_barrier(0);
  body(cur);

  // all waves done with staging before overlaying merge buffers
  __syncthreads();
  #pragma unroll
  for (int r = 0; r < 16; r++){
    int qq = (r&3) + 8*(r>>2) + 4*hi;
    sh.m.O[w][qq][l31]      = o0[r];
    sh.m.O[w][qq][32 + l31] = o1[r];
  }
  if (lane < 32){ sh.m.M[w][l31] = m2; sh.m.L[w][l31] = lsum; }
  __syncthreads();

  // merge 3 kv-split partials and store
  for (int t = threadIdx.x; t < 32*ND; t += 192){
    int qq = t / ND, d = t - (t / ND) * ND;
    float mA = sh.m.M[0][qq], mB = sh.m.M[1][qq], mC = sh.m.M[2][qq];
    float M = fmaxf(fmaxf(mA, mB), mC);
    float eA = ex2(mA - M), eB = ex2(mB - M), eC = ex2(mC - M);
    float L = sh.m.L[0][qq]*eA + sh.m.L[1][qq]*eB + sh.m.L[2][qq]*eC;
    float O = sh.m.O[0][qq][d]*eA + sh.m.O[1][qq][d]*eB + sh.m.O[2][qq][d]*eC;
    ao[(size_t)(b*NS + q0 + qq)*NC + h*ND + d] = f2bf(O / L);
  }
}

// ---- output projection + bias + residual (fp32 out) ----
__global__ __launch_bounds__(256) void k_out(const unsigned short* __restrict__ ao,
    const unsigned short* __restrict__ woT, const float* __restrict__ bo,
    const float* __restrict__ hs, float* __restrict__ out){
  int wave = threadIdx.x >> 6, lane = threadIdx.x & 63;
  int lane16 = lane & 15, grp = lane >> 4;
  int m0 = blockIdx.x * 64, n0 = blockIdx.y * 64;
  int arow = m0 + wave*16 + lane16;
  f32x4 acc[4];
  #pragma unroll
  for (int t = 0; t < 4; t++) acc[t] = (f32x4){0.f,0.f,0.f,0.f};
  #pragma unroll
  for (int k0 = 0; k0 < NC; k0 += 32){
    bf16x8 a = *(const bf16x8*)&ao[arow*NC + k0 + grp*8];
    #pragma unroll
    for (int t = 0; t < 4; t++){
      bf16x8 b = *(const bf16x8*)&woT[(n0 + t*16 + lane16)*NC + k0 + grp*8];
      acc[t] = MFMA16(a, b, acc[t]);
    }
  }
  int crow = m0 + wave*16 + grp*4;
  #pragma unroll
  for (int t = 0; t < 4; t++){
    int cc = n0 + t*16 + lane16;
    #pragma unroll
    for (int r = 0; r < 4; r++){
      int rr = crow + r;
      out[rr*NC + cc] = acc[t][r] + bo[cc] + hs[rr*NC + cc];
    }
  }
}

extern "C" void kernel_launch(void* const* d_in, const int* in_sizes, int n_in,
                              void* d_out, int out_size, void* d_ws, size_t ws_size,
                              hipStream_t stream){
  const float* hs = (const float*)d_in[0];
  const float* Wq = (const float*)d_in[1];
  const float* Wk = (const float*)d_in[2];
  const float* Wv = (const float*)d_in[3];
  const float* Wo = (const float*)d_in[4];
  const float* bo = (const float*)d_in[5];
  const int*  ids = (const int*)d_in[6];
  float* out = (float*)d_out;

  unsigned short* hsb = (unsigned short*)d_ws;        // aliased: ao reuses hsb
  unsigned short* wqT = hsb + (size_t)NBS*NC;
  unsigned short* wkT = wqT + (size_t)NC*NC;
  unsigned short* wvT = wkT + (size_t)NC*NC;
  unsigned short* woT = wvT + (size_t)NC*NC;
  unsigned short* qb  = woT + (size_t)NC*NC;          // [NBS][384] padded
  unsigned short* kb  = qb  + (size_t)NBS*QSTR;       // [160][8][2048] swizzled
  unsigned short* vT  = kb  + (size_t)(NBS/32)*NH*TSH; // [160][8][2048] swizzled
  unsigned short* ao  = hsb;                          // safe: hsb dead after k_qkv

  k_conv_hs<<<dim3(NBS*NC/1024), dim3(256), 0, stream>>>(hs, hsb);
  k_conv_w<<<dim3(NC/16, NC/16, 4), dim3(16,16), 0, stream>>>(Wq, Wk, Wv, Wo, wqT, wkT, wvT, woT);
  k_zero_qbpad<<<dim3(NBS*NH/256), dim3(256), 0, stream>>>(qb);
  k_qkv<<<dim3(NBS/64, NC/64, 3), dim3(256), 0, stream>>>(hsb, wqT, wkT, wvT, qb, kb, vT);
  k_attn<<<dim3((NS/32)*NH, 1, NB), dim3(192), 0, stream>>>(qb, kb, vT, ids, ao);
  k_out<<<dim3(NBS/64, NC/64, 1), dim3(256), 0, stream>>>(ao, woT, bo, hs, out);
}